// Round 1
// 348.114 us; speedup vs baseline: 1.4239x; 1.4239x over previous
//
#include <hip/hip_runtime.h>
#include <math.h>

// ---------------- problem constants ----------------
#define TASKS 64
#define NB    4096
#define TDI   512     // token dim (K of GEMM1)
#define HDI   256     // hidden dim
#define VDI   484     // visual dim (padded to 512; row 484 = wc = W2^T.c fused dot column)

// ---------------- ws layout (bytes): frag-order (pre-swizzled) fp16 arrays ----------------
// tf : [64 rb][16 ks][4 rt][4 q][16 l15][8h]  f16  (4 MB)   unit strides: l15=1,q=16,rt=64,ks=256,rb=4096
// w1 : [64 t][4 w][16 ks][4 ct][4 q][16 l15][8h]   (16 MB)  strides: q=16,ct=64,ks=256,w=4096,t=16384
// w2 : [64 t][2 p][4 w][8 ks][4 ct][4 q][16 l15][8h] (16MB)  strides: q=16,ct=64,ks=256,w=2048,p=8192,t=16384
#define WS_TF   ((size_t)0)
#define WS_W1   ((size_t)4194304)
#define WS_W2   ((size_t)20971520)
#define WS_CN   ((size_t)37748736)                // 64 f32 centroid norms
#define WS_BC   ((size_t)37748992)                // 64 f32 b2.c
#define WS_ACC  ((size_t)37749248)                // 64 f32 distance accumulators

// ---------------- LDS layout (bytes): 37376 total ----------------
// HP: [8 ks][4 rt][4 q][16 l15][8h] f16 = 32768  (frag-order for GEMM2 A)
#define LDS_HP 0
#define LDS_B2 32768      // 512 f32: b2 (col 484 = b2.c, 485.. = 0)
#define LDS_R0 34816      // 256 f32: [4w][64m]
#define LDS_R1 35840      // 256 f32
#define LDS_MU 36864      // 64 f32
#define LDS_RS 37120      // 64 f32
#define SMEM_BYTES 37376

typedef _Float16 half8 __attribute__((ext_vector_type(8)));
typedef float    f32x4 __attribute__((ext_vector_type(4)));

#define MFMA16(a, b, c) __builtin_amdgcn_mfma_f32_16x16x32_f16((a), (b), (c), 0, 0, 0)

__device__ __forceinline__ half8 cvt8(float4 v0, float4 v1) {
  half8 r;
  r[0]=(_Float16)v0.x; r[1]=(_Float16)v0.y; r[2]=(_Float16)v0.z; r[3]=(_Float16)v0.w;
  r[4]=(_Float16)v1.x; r[5]=(_Float16)v1.y; r[6]=(_Float16)v1.z; r[7]=(_Float16)v1.w;
  return r;
}

// Exact-GELU via Abramowitz-Stegun 7.1.26 erf (|err| <= 1.5e-7), ~14 VALU ops,
// branch-free; v_rcp/v_exp via asm (1-ulp approx is far inside fp16 noise).
__device__ __forceinline__ float gelu_exact(float x) {
  float az = fabsf(x) * 0.70710678118654752f;          // |x|/sqrt(2)
  float d  = fmaf(0.3275911f, az, 1.0f);
  float t; asm("v_rcp_f32 %0, %1" : "=v"(t) : "v"(d));
  float p  = fmaf(t, 1.061405429f, -1.453152027f);
  p = fmaf(t, p, 1.421413741f);
  p = fmaf(t, p, -0.284496736f);
  p = fmaf(t, p, 0.254829592f);
  p = p * t;
  float m = az * az * -1.4426950408889634f;            // -z^2 * log2(e)
  float e; asm("v_exp_f32 %0, %1" : "=v"(e) : "v"(m)); // 2^m = exp(-z^2)
  float er = fmaf(-p, e, 1.0f);                        // erf(|z|)
  er = copysignf(er, x);
  float hx = 0.5f * x;
  return fmaf(hx, er, hx);                             // 0.5*x*(1+erf)
}

// ================= prepass: fp32 -> frag-order fp16 =================
extern "C" __global__ void prep_all(const float* __restrict__ t_feat,
                                    const float* __restrict__ W1,
                                    const float* __restrict__ W2,
                                    const float* __restrict__ b2,
                                    const float* __restrict__ cent,
                                    _Float16* __restrict__ tf,
                                    _Float16* __restrict__ w1,
                                    _Float16* __restrict__ w2,
                                    float* __restrict__ cnorm,
                                    float* __restrict__ bc,
                                    float* __restrict__ accum) {
  const int bid = blockIdx.x, tid = threadIdx.x;
  __shared__ float redc[256], redb[256];
  if (bid < 1024) {                       // t_feat -> tf, 262144 half8 units
    int u = bid * 256 + tid;
    int row = u >> 6, k8 = u & 63;        // f32 idx = u*8 (coalesced reads)
    float4 v0 = ((const float4*)t_feat)[u * 2];
    float4 v1 = ((const float4*)t_feat)[u * 2 + 1];
    int rb = row >> 6, rt = (row >> 4) & 3, l15 = row & 15, ks = k8 >> 2, q = k8 & 3;
    size_t o = (size_t)rb * 4096 + ks * 256 + rt * 64 + q * 16 + l15;
    *(half8*)(tf + o * 8) = cvt8(v0, v1);
  } else if (bid < 5120) {                // W1 -> w1, 1048576 units
    int u = (bid - 1024) * 256 + tid;
    int t = u >> 14, rem = u & 16383, hd = rem >> 6, k8 = rem & 63;
    float4 v0 = ((const float4*)W1)[u * 2];
    float4 v1 = ((const float4*)W1)[u * 2 + 1];
    int w_ = hd >> 6, ct = (hd >> 4) & 3, l15 = hd & 15, ks = k8 >> 2, q = k8 & 3;
    size_t o = (size_t)t * 16384 + w_ * 4096 + ks * 256 + ct * 64 + q * 16 + l15;
    *(half8*)(w1 + o * 8) = cvt8(v0, v1);
  } else if (bid < 9216) {                // W2 rows (incl. zero pad 485..511) -> w2
    int u = (bid - 5120) * 256 + tid;
    int t = u >> 14, rem = u & 16383, vd = rem >> 5, k8 = rem & 31;
    half8 hv;
    if (vd < 484) {
      float4 v0 = ((const float4*)W2)[(size_t)(t * 484 + vd) * 64 + k8 * 2];
      float4 v1 = ((const float4*)W2)[(size_t)(t * 484 + vd) * 64 + k8 * 2 + 1];
      hv = cvt8(v0, v1);
    } else if (vd >= 485) {
      #pragma unroll
      for (int i = 0; i < 8; ++i) hv[i] = (_Float16)0.f;
    } else {
      return;                             // vd==484: wc row written by per-task block
    }
    int pass = vd >> 8, w_ = (vd >> 6) & 3, ct = (vd >> 4) & 3, l15 = vd & 15;
    int ks = k8 >> 2, q = k8 & 3;
    size_t o = (size_t)t * 16384 + pass * 8192 + w_ * 2048 + ks * 256 + ct * 64 + q * 16 + l15;
    *(half8*)(w2 + o * 8) = hv;
  } else {                                // per-task: wc row, cnorm, b2.c, accum init
    int t = bid - 9216;
    int h = tid;                          // 0..255
    float wcv = 0.f;
    for (int v = 0; v < VDI; ++v)
      wcv += W2[((size_t)t * VDI + v) * HDI + h] * cent[(size_t)t * VDI + v];
    // vd=484 -> pass=1, w=3, ct=2, l15=4 ; k8 = h>>3, within-unit h&7
    {
      int ks = h >> 5, q = (h >> 3) & 3;
      size_t o = (size_t)t * 16384 + 8192 + 3 * 2048 + ks * 256 + 2 * 64 + q * 16 + 4;
      w2[o * 8 + (h & 7)] = (_Float16)wcv;
    }
    float c2 = 0.f, b2c = 0.f;
    for (int v = h; v < VDI; v += 256) {
      float c = cent[(size_t)t * VDI + v];
      c2 += c * c;
      b2c += b2[(size_t)t * VDI + v] * c;
    }
    redc[tid] = c2; redb[tid] = b2c;
    __syncthreads();
    if (tid < 64) {
      c2  = redc[tid] + redc[tid + 64] + redc[tid + 128] + redc[tid + 192];
      b2c = redb[tid] + redb[tid + 64] + redb[tid + 128] + redb[tid + 192];
      #pragma unroll
      for (int off = 32; off; off >>= 1) { c2 += __shfl_xor(c2, off); b2c += __shfl_xor(b2c, off); }
      if (tid == 0) { cnorm[t] = sqrtf(c2); bc[t] = b2c; accum[t] = 0.f; }
    }
  }
}

// ============ fused main: 256 thr / 4 waves / 64x64 per wave, 4 blocks/CU target ============
// Staggered-B pipeline: B frags single-buffered per-ct (reload right after last use ->
// constant 12-MFMA issue->use gap); A frags double-buffered (1-STEP gap). 48 frag VGPRs
// + 64 acc AGPRs keeps unified usage <=128 -> 4 waves/EU.

#define STEP_RELOAD(A, ACC, PB) do {                                           \
  _Pragma("unroll") for (int ct_ = 0; ct_ < 4; ++ct_) {                        \
    ACC[0][ct_] = MFMA16(A[0], b[ct_], ACC[0][ct_]);                           \
    ACC[1][ct_] = MFMA16(A[1], b[ct_], ACC[1][ct_]);                           \
    ACC[2][ct_] = MFMA16(A[2], b[ct_], ACC[2][ct_]);                           \
    ACC[3][ct_] = MFMA16(A[3], b[ct_], ACC[3][ct_]);                           \
    b[ct_] = (PB)[ct_ * 64];                                                   \
  } } while (0)

#define STEP_LAST(A, ACC) do {                                                 \
  _Pragma("unroll") for (int ct_ = 0; ct_ < 4; ++ct_) {                        \
    ACC[0][ct_] = MFMA16(A[0], b[ct_], ACC[0][ct_]);                           \
    ACC[1][ct_] = MFMA16(A[1], b[ct_], ACC[1][ct_]);                           \
    ACC[2][ct_] = MFMA16(A[2], b[ct_], ACC[2][ct_]);                           \
    ACC[3][ct_] = MFMA16(A[3], b[ct_], ACC[3][ct_]);                           \
  } } while (0)

#define LD_A4(D, P) do { D[0] = (P)[0]; D[1] = (P)[64]; D[2] = (P)[128]; D[3] = (P)[192]; } while (0)

extern "C" __global__ void __launch_bounds__(256, 4)
router_main(const half8* __restrict__ tfv,
            const half8* __restrict__ w1v,
            const half8* __restrict__ w2v,
            const float* __restrict__ b1,
            const float* __restrict__ gamma,
            const float* __restrict__ beta,
            const float* __restrict__ b2,
            const float* __restrict__ bc,
            const float* __restrict__ cnorm,
            float* __restrict__ accum) {
  __shared__ __align__(16) char smem[SMEM_BYTES];

  const int tid = threadIdx.x;
  const int bx  = blockIdx.x;
  // XCD swizzle: each XCD (bx&7) works one task at a time -> task weights L2-resident.
  const int t  = ((bx & 7) << 3) | (bx >> 9);
  const int rb = (bx >> 3) & 63;

  const int lane = tid & 63;
  const int w    = tid >> 6;       // wave id 0..3
  const int quad = lane >> 4;
  const int l15  = lane & 15;

  // ---- preload b2 (+b2.c at col 484) into LDS ----
  {
    float* b2s = (float*)(smem + LDS_B2);
    int i0 = tid;
    b2s[i0] = (i0 < VDI) ? b2[(size_t)t * VDI + i0] : 0.f;
    int i1 = tid + 256;
    float v = 0.f;
    if (i1 < VDI) v = b2[(size_t)t * VDI + i1];
    else if (i1 == VDI) v = bc[t];
    b2s[i1] = v;
  }
  float b1v[4];
  #pragma unroll
  for (int ct = 0; ct < 4; ++ct)
    b1v[ct] = b1[t * HDI + w * 64 + ct * 16 + l15];

  f32x4 zero4 = {0.f, 0.f, 0.f, 0.f};
  f32x4 acc[4][4];
  #pragma unroll
  for (int rt = 0; rt < 4; ++rt)
    #pragma unroll
    for (int ct = 0; ct < 4; ++ct) acc[rt][ct] = zero4;

  half8 a0[4], a1[4], b[4];

  // ================= Phase 1: GEMM1 (K=512), barrier-free, frags direct from L2 =================
  {
    const half8* pa = tfv + ((size_t)rb * 4096 + quad * 16 + l15);
    const half8* pb = w1v + ((size_t)t * 16384 + w * 4096 + quad * 16 + l15);
    LD_A4(a0, pa);                                     // ks0
    b[0] = pb[0]; b[1] = pb[64]; b[2] = pb[128]; b[3] = pb[192];   // ks0
    a1[0] = pa[256]; a1[1] = pa[320]; a1[2] = pa[384]; a1[3] = pa[448]; // ks1
    pa += 512;            // next A load = ks2
    pb += 256;            // next B load = ks1
    #pragma unroll 1
    for (int ks = 0; ks < 14; ks += 2) {
      STEP_RELOAD(a0, acc, pb); pb += 256;   // uses ks, b <- ks+1
      LD_A4(a0, pa);            pa += 256;   // a0 <- ks+2
      STEP_RELOAD(a1, acc, pb); pb += 256;   // uses ks+1, b <- ks+2
      LD_A4(a1, pa);            pa += 256;   // a1 <- ks+3
    }
    STEP_RELOAD(a0, acc, pb);                // ks14, b <- ks15
    STEP_LAST(a1, acc);                      // ks15
  }

  // ================= Phase 2: +b1, LayerNorm, exact GELU -> H' (frag-order f16) in LDS =================
  // gamma/beta loads issued here (latency hidden behind pass A + stats barrier) to keep
  // phase-1 register pressure <=128.
  float gv[4], bev[4];
  #pragma unroll
  for (int ct = 0; ct < 4; ++ct) {
    gv[ct]  = gamma[t * HDI + w * 64 + ct * 16 + l15];
    bev[ct] = beta [t * HDI + w * 64 + ct * 16 + l15];
  }
  {
    float* red0 = (float*)(smem + LDS_R0);
    float* red1 = (float*)(smem + LDS_R1);
    #pragma unroll
    for (int rt = 0; rt < 4; ++rt)
      #pragma unroll
      for (int r = 0; r < 4; ++r) {
        float sv = 0.f, qv = 0.f;
        #pragma unroll
        for (int ct = 0; ct < 4; ++ct) {
          float v = acc[rt][ct][r] + b1v[ct];
          acc[rt][ct][r] = v;
          sv += v; qv += v * v;
        }
        sv += __shfl_xor(sv, 1); qv += __shfl_xor(qv, 1);
        sv += __shfl_xor(sv, 2); qv += __shfl_xor(qv, 2);
        sv += __shfl_xor(sv, 4); qv += __shfl_xor(qv, 4);
        sv += __shfl_xor(sv, 8); qv += __shfl_xor(qv, 8);
        if (l15 == 0) {
          int m = rt * 16 + quad * 4 + r;
          red0[w * 64 + m] = sv;
          red1[w * 64 + m] = qv;
        }
      }
    __syncthreads();
    if (tid < 64) {
      float s = red0[tid] + red0[64 + tid] + red0[128 + tid] + red0[192 + tid];
      float q = red1[tid] + red1[64 + tid] + red1[128 + tid] + red1[192 + tid];
      float mu = s * (1.f / HDI);
      float var = q * (1.f / HDI) - mu * mu;
      ((float*)(smem + LDS_MU))[tid] = mu;
      ((float*)(smem + LDS_RS))[tid] = rsqrtf(var + 1e-5f);
    }
    __syncthreads();
    const float* mus = (const float*)(smem + LDS_MU);
    const float* rss = (const float*)(smem + LDS_RS);
    #pragma unroll
    for (int rt = 0; rt < 4; ++rt)
      #pragma unroll
      for (int ct = 0; ct < 4; ++ct) {
        int col = w * 64 + ct * 16 + l15;
        // HP[ks2][rt][quad2][m&15][col&7]: ks2=col>>5, quad2=(col>>3)&3, m&15=quad*4+r
        int base = (((col >> 5) * 4 + rt) * 4 + ((col >> 3) & 3)) * 256
                 + quad * 64 + (l15 & 7) * 2;
        #pragma unroll
        for (int r = 0; r < 4; ++r) {
          int m = rt * 16 + quad * 4 + r;
          float x = (acc[rt][ct][r] - mus[m]) * rss[m];
          x = x * gv[ct] + bev[ct];
          float g = gelu_exact(x);
          *(_Float16*)(smem + LDS_HP + base + r * 16) = (_Float16)g;
        }
      }
    __syncthreads();
  }

  // ================= Phase 3: GEMM2 (2 N-passes of 256, incl. fused wc dot column) =================
  {
    const float* b2s = (const float*)(smem + LDS_B2);
    float* red0 = (float*)(smem + LDS_R0);
    float* red1 = (float*)(smem + LDS_R1);
    const char* ha = smem + LDS_HP + quad * 256 + l15 * 16;

    #pragma unroll 1
    for (int pass = 0; pass < 2; ++pass) {
      const half8* pc = w2v + ((size_t)t * 16384 + pass * 8192 + w * 2048 + quad * 16 + l15);
      f32x4 acc2[4][4];
      #pragma unroll
      for (int rt = 0; rt < 4; ++rt)
        #pragma unroll
        for (int ct = 0; ct < 4; ++ct) acc2[rt][ct] = zero4;

      a0[0] = *(const half8*)(ha);        a0[1] = *(const half8*)(ha + 1024);
      a0[2] = *(const half8*)(ha + 2048); a0[3] = *(const half8*)(ha + 3072);
      b[0] = pc[0]; b[1] = pc[64]; b[2] = pc[128]; b[3] = pc[192];
      a1[0] = *(const half8*)(ha + 4096); a1[1] = *(const half8*)(ha + 5120);
      a1[2] = *(const half8*)(ha + 6144); a1[3] = *(const half8*)(ha + 7168);
      pc += 256;
      #pragma unroll 1
      for (int ks = 0; ks < 6; ks += 2) {
        STEP_RELOAD(a0, acc2, pc); pc += 256;
        {
          const char* h2 = ha + (ks + 2) * 4096;
          a0[0] = *(const half8*)(h2);        a0[1] = *(const half8*)(h2 + 1024);
          a0[2] = *(const half8*)(h2 + 2048); a0[3] = *(const half8*)(h2 + 3072);
        }
        STEP_RELOAD(a1, acc2, pc); pc += 256;
        {
          const char* h3 = ha + (ks + 3) * 4096;
          a1[0] = *(const half8*)(h3);        a1[1] = *(const half8*)(h3 + 1024);
          a1[2] = *(const half8*)(h3 + 2048); a1[3] = *(const half8*)(h3 + 3072);
        }
      }
      STEP_RELOAD(a0, acc2, pc);   // ks6, b <- ks7
      STEP_LAST(a1, acc2);         // ks7

      // epilogue: per-row |v|^2 (cols<484) and dot (col 484 = wc column + b2.c)
      #pragma unroll
      for (int rt = 0; rt < 4; ++rt)
        #pragma unroll
        for (int r = 0; r < 4; ++r) {
          float ssq = 0.f, dtv = 0.f;
          #pragma unroll
          for (int ct = 0; ct < 4; ++ct) {
            int vcol = pass * 256 + w * 64 + ct * 16 + l15;
            float val = acc2[rt][ct][r] + b2s[vcol];
            ssq += (vcol < VDI) ? val * val : 0.f;
            dtv += (vcol == VDI) ? val : 0.f;
          }
          ssq += __shfl_xor(ssq, 1); dtv += __shfl_xor(dtv, 1);
          ssq += __shfl_xor(ssq, 2); dtv += __shfl_xor(dtv, 2);
          ssq += __shfl_xor(ssq, 4); dtv += __shfl_xor(dtv, 4);
          ssq += __shfl_xor(ssq, 8); dtv += __shfl_xor(dtv, 8);
          if (l15 == 0) {
            int m = rt * 16 + quad * 4 + r;
            if (pass == 0) {
              red0[w * 64 + m] = ssq;
            } else {
              red0[w * 64 + m] += ssq;
              red1[w * 64 + m] = dtv;
            }
          }
        }
    }

    __syncthreads();
    if (tid < 64) {
      float ss  = red0[tid] + red0[64 + tid] + red0[128 + tid] + red0[192 + tid];
      float dot = red1[tid] + red1[64 + tid] + red1[128 + tid] + red1[192 + tid];
      float cn = fmaxf(cnorm[t], 1e-8f);
      float vn = fmaxf(sqrtf(ss), 1e-8f);
      float part = 1.0f - dot / (vn * cn);
      part += __shfl_down(part, 32);
      part += __shfl_down(part, 16);
      part += __shfl_down(part, 8);
      part += __shfl_down(part, 4);
      part += __shfl_down(part, 2);
      part += __shfl_down(part, 1);
      if (tid == 0) atomicAdd(accum + t, part);
    }
  }
}

// ================= finalize: mean, argmin =================
extern "C" __global__ void finalize_k(const float* __restrict__ accum, float* __restrict__ out) {
  int t = threadIdx.x;                               // <<<1, 64>>>
  float d = accum[t] * (1.0f / (float)NB);
  out[t] = d;
  float bd = d; int bi = t;
  #pragma unroll
  for (int off = 32; off; off >>= 1) {
    float od = __shfl_xor(bd, off);
    int   oi = __shfl_xor(bi, off);
    if (od < bd || (od == bd && oi < bi)) { bd = od; bi = oi; }   // first-min tie-break
  }
  if (t == 0) out[64] = (float)bi;
}

extern "C" void kernel_launch(void* const* d_in, const int* in_sizes, int n_in,
                              void* d_out, int out_size, void* d_ws, size_t ws_size,
                              hipStream_t stream) {
  const float* t_feat = (const float*)d_in[0];
  const float* W1     = (const float*)d_in[1];
  const float* b1     = (const float*)d_in[2];
  const float* gamma  = (const float*)d_in[3];
  const float* beta   = (const float*)d_in[4];
  const float* W2     = (const float*)d_in[5];
  const float* b2     = (const float*)d_in[6];
  const float* cent   = (const float*)d_in[7];

  char* ws = (char*)d_ws;   // requires ws_size >= ~38 MiB
  _Float16* tf = (_Float16*)(ws + WS_TF);
  _Float16* w1 = (_Float16*)(ws + WS_W1);
  _Float16* w2 = (_Float16*)(ws + WS_W2);
  float* cnorm = (float*)(ws + WS_CN);
  float* bc    = (float*)(ws + WS_BC);
  float* accum = (float*)(ws + WS_ACC);
  float* out = (float*)d_out;

  prep_all<<<9280, 256, 0, stream>>>(t_feat, W1, W2, b2, cent,
                                     tf, w1, w2, cnorm, bc, accum);
  router_main<<<4096, 256, 0, stream>>>((const half8*)tf, (const half8*)w1, (const half8*)w2,
                                        b1, gamma, beta, b2, bc, cnorm, accum);
  finalize_k<<<1, 64, 0, stream>>>(accum, out);
}

// Round 2
// 344.546 us; speedup vs baseline: 1.4386x; 1.0104x over previous
//
#include <hip/hip_runtime.h>
#include <math.h>

// ---------------- problem constants ----------------
#define TASKS 64
#define NB    4096
#define TDI   512     // token dim (K of GEMM1)
#define HDI   256     // hidden dim
#define VDI   484     // visual dim (padded to 512; row 484 = wc = W2^T.c fused dot column)

// ---------------- ws layout (bytes): frag-order (pre-swizzled) fp16 arrays ----------------
// tf : [64 rb][16 ks][4 rt][4 q][16 l15][8h]  f16  (4 MB)   unit strides: l15=1,q=16,rt=64,ks=256,rb=4096
// w1 : [64 t][4 w][16 ks][4 ct][4 q][16 l15][8h]   (16 MB)  strides: q=16,ct=64,ks=256,w=4096,t=16384
// w2 : [64 t][2 p][4 w][8 ks][4 ct][4 q][16 l15][8h] (16MB)  strides: q=16,ct=64,ks=256,w=2048,p=8192,t=16384
#define WS_TF   ((size_t)0)
#define WS_W1   ((size_t)4194304)
#define WS_W2   ((size_t)20971520)
#define WS_CN   ((size_t)37748736)                // 64 f32 centroid norms
#define WS_BC   ((size_t)37748992)                // 64 f32 b2.c
#define WS_ACC  ((size_t)37749248)                // 64 f32 distance accumulators

// ---------------- LDS layout (bytes): 37376 total ----------------
// HP: [8 ks][4 rt][4 q][16 l15][8h] f16 = 32768  (frag-order for GEMM2 A)
#define LDS_HP 0
#define LDS_B2 32768      // 512 f32: b2 (col 484 = b2.c, 485.. = 0)
#define LDS_R0 34816      // 256 f32: [4w][64m]
#define LDS_R1 35840      // 256 f32
#define LDS_MU 36864      // 64 f32
#define LDS_RS 37120      // 64 f32
#define SMEM_BYTES 37376

typedef _Float16 half8 __attribute__((ext_vector_type(8)));
typedef float    f32x4 __attribute__((ext_vector_type(4)));

#define MFMA16(a, b, c) __builtin_amdgcn_mfma_f32_16x16x32_f16((a), (b), (c), 0, 0, 0)

__device__ __forceinline__ half8 cvt8(float4 v0, float4 v1) {
  half8 r;
  r[0]=(_Float16)v0.x; r[1]=(_Float16)v0.y; r[2]=(_Float16)v0.z; r[3]=(_Float16)v0.w;
  r[4]=(_Float16)v1.x; r[5]=(_Float16)v1.y; r[6]=(_Float16)v1.z; r[7]=(_Float16)v1.w;
  return r;
}

// Exact-GELU via Abramowitz-Stegun 7.1.26 erf (|err| <= 1.5e-7), ~14 VALU ops, branch-free.
__device__ __forceinline__ float gelu_exact(float x) {
  float az = fabsf(x) * 0.70710678118654752f;          // |x|/sqrt(2)
  float d  = fmaf(0.3275911f, az, 1.0f);
  float t; asm("v_rcp_f32 %0, %1" : "=v"(t) : "v"(d));
  float p  = fmaf(t, 1.061405429f, -1.453152027f);
  p = fmaf(t, p, 1.421413741f);
  p = fmaf(t, p, -0.284496736f);
  p = fmaf(t, p, 0.254829592f);
  p = p * t;
  float m = az * az * -1.4426950408889634f;            // -z^2 * log2(e)
  float e; asm("v_exp_f32 %0, %1" : "=v"(e) : "v"(m)); // 2^m = exp(-z^2)
  float er = fmaf(-p, e, 1.0f);                        // erf(|z|)
  er = copysignf(er, x);
  float hx = 0.5f * x;
  return fmaf(hx, er, hx);                             // 0.5*x*(1+erf)
}

// ================= prepass: fp32 -> frag-order fp16 =================
// OUTPUT-linear thread mapping: every store is a fully-coalesced 16B write
// (waves write contiguous 4KB); reads gather at 32B granule (2x float4).
extern "C" __global__ void prep_all(const float* __restrict__ t_feat,
                                    const float* __restrict__ W1,
                                    const float* __restrict__ W2,
                                    const float* __restrict__ b2,
                                    const float* __restrict__ cent,
                                    _Float16* __restrict__ tf,
                                    _Float16* __restrict__ w1,
                                    _Float16* __restrict__ w2,
                                    float* __restrict__ cnorm,
                                    float* __restrict__ bc,
                                    float* __restrict__ accum) {
  const int bid = blockIdx.x, tid = threadIdx.x;
  __shared__ float redc[256], redb[256];
  if (bid < 1024) {                       // t_feat -> tf, 262144 half8 units
    int p = bid * 256 + tid;
    int rb = p >> 12, r = p & 4095;
    int ks = r >> 8, rt = (r >> 6) & 3, q = (r >> 4) & 3, l15 = r & 15;
    int row = rb * 64 + rt * 16 + l15, k8 = ks * 4 + q;
    float4 v0 = ((const float4*)t_feat)[(row * 64 + k8) * 2];
    float4 v1 = ((const float4*)t_feat)[(row * 64 + k8) * 2 + 1];
    *(half8*)(tf + (size_t)p * 8) = cvt8(v0, v1);
  } else if (bid < 5120) {                // W1 -> w1, 1048576 units
    int p = (bid - 1024) * 256 + tid;
    int t = p >> 14, r = p & 16383;
    int w_ = r >> 12, ks = (r >> 8) & 15, ct = (r >> 6) & 3, q = (r >> 4) & 3, l15 = r & 15;
    int hd = w_ * 64 + ct * 16 + l15, k8 = ks * 4 + q;
    float4 v0 = ((const float4*)W1)[((size_t)(t * 256 + hd) * 64 + k8) * 2];
    float4 v1 = ((const float4*)W1)[((size_t)(t * 256 + hd) * 64 + k8) * 2 + 1];
    *(half8*)(w1 + (size_t)p * 8) = cvt8(v0, v1);
  } else if (bid < 9216) {                // W2 -> w2 (padded), 1048576 units
    int p = (bid - 5120) * 256 + tid;
    int t = p >> 14, r = p & 16383;
    int pass = r >> 13, w_ = (r >> 11) & 3, ks = (r >> 8) & 7;
    int ct = (r >> 6) & 3, q = (r >> 4) & 3, l15 = r & 15;
    int vd = pass * 256 + w_ * 64 + ct * 16 + l15, k8 = ks * 4 + q;
    half8 hv;
    if (vd < 484) {
      float4 v0 = ((const float4*)W2)[((size_t)(t * 484 + vd) * 64 + k8 * 2)];
      float4 v1 = ((const float4*)W2)[((size_t)(t * 484 + vd) * 64 + k8 * 2) + 1];
      hv = cvt8(v0, v1);
    } else if (vd >= 485) {
      #pragma unroll
      for (int i = 0; i < 8; ++i) hv[i] = (_Float16)0.f;
    } else {
      return;                             // vd==484: wc row written by per-task block
    }
    *(half8*)(w2 + (size_t)p * 8) = hv;
  } else {                                // per-task: wc row, cnorm, b2.c, accum init
    int t = bid - 9216;
    int h = tid;                          // 0..255
    float wcv = 0.f;
    for (int v = 0; v < VDI; ++v)
      wcv += W2[((size_t)t * VDI + v) * HDI + h] * cent[(size_t)t * VDI + v];
    // vd=484 -> pass=1, w=3, ct=2, l15=4 ; ks = h>>5, q=(h>>3)&3, within-unit h&7
    {
      int ks = h >> 5, q = (h >> 3) & 3;
      size_t o = (size_t)t * 16384 + 8192 + 3 * 2048 + ks * 256 + 2 * 64 + q * 16 + 4;
      w2[o * 8 + (h & 7)] = (_Float16)wcv;
    }
    float c2 = 0.f, b2c = 0.f;
    for (int v = h; v < VDI; v += 256) {
      float c = cent[(size_t)t * VDI + v];
      c2 += c * c;
      b2c += b2[(size_t)t * VDI + v] * c;
    }
    redc[tid] = c2; redb[tid] = b2c;
    __syncthreads();
    if (tid < 64) {
      c2  = redc[tid] + redc[tid + 64] + redc[tid + 128] + redc[tid + 192];
      b2c = redb[tid] + redb[tid + 64] + redb[tid + 128] + redb[tid + 192];
      #pragma unroll
      for (int off = 32; off; off >>= 1) { c2 += __shfl_xor(c2, off); b2c += __shfl_xor(b2c, off); }
      if (tid == 0) { cnorm[t] = sqrtf(c2); bc[t] = b2c; accum[t] = 0.f; }
    }
  }
}

// ============ fused main: 256 thr / 4 waves / 64x64 per wave, 4 blocks/CU ============
// Spill-free phase 1: NOTHING is loaded before phase 1 except the frag pointers.
// Live set = acc(64) + a0/a1/b(48) + pa/pb(4) + lane math ~= 124 < 128 regs.
// b1/gamma/beta/b2-LDS-preload all deferred into phase 2 (latency hidden by the
// stats barrier). s_setprio(1) around MFMA clusters: 4 independent blocks/CU sit
// at different phases (GEMM vs LN/GELU) -> role-diverse regime where T5 pays.

#define STEP_RELOAD(A, ACC, PB) do {                                           \
  __builtin_amdgcn_s_setprio(1);                                               \
  _Pragma("unroll") for (int ct_ = 0; ct_ < 4; ++ct_) {                        \
    ACC[0][ct_] = MFMA16(A[0], b[ct_], ACC[0][ct_]);                           \
    ACC[1][ct_] = MFMA16(A[1], b[ct_], ACC[1][ct_]);                           \
    ACC[2][ct_] = MFMA16(A[2], b[ct_], ACC[2][ct_]);                           \
    ACC[3][ct_] = MFMA16(A[3], b[ct_], ACC[3][ct_]);                           \
    b[ct_] = (PB)[ct_ * 64];                                                   \
  }                                                                            \
  __builtin_amdgcn_s_setprio(0);                                               \
} while (0)

#define STEP_LAST(A, ACC) do {                                                 \
  __builtin_amdgcn_s_setprio(1);                                               \
  _Pragma("unroll") for (int ct_ = 0; ct_ < 4; ++ct_) {                        \
    ACC[0][ct_] = MFMA16(A[0], b[ct_], ACC[0][ct_]);                           \
    ACC[1][ct_] = MFMA16(A[1], b[ct_], ACC[1][ct_]);                           \
    ACC[2][ct_] = MFMA16(A[2], b[ct_], ACC[2][ct_]);                           \
    ACC[3][ct_] = MFMA16(A[3], b[ct_], ACC[3][ct_]);                           \
  }                                                                            \
  __builtin_amdgcn_s_setprio(0);                                               \
} while (0)

#define LD_A4(D, P) do { D[0] = (P)[0]; D[1] = (P)[64]; D[2] = (P)[128]; D[3] = (P)[192]; } while (0)

extern "C" __global__ void __launch_bounds__(256, 4)
router_main(const half8* __restrict__ tfv,
            const half8* __restrict__ w1v,
            const half8* __restrict__ w2v,
            const float* __restrict__ b1,
            const float* __restrict__ gamma,
            const float* __restrict__ beta,
            const float* __restrict__ b2,
            const float* __restrict__ bc,
            const float* __restrict__ cnorm,
            float* __restrict__ accum) {
  __shared__ __align__(16) char smem[SMEM_BYTES];

  const int tid = threadIdx.x;
  const int bx  = blockIdx.x;
  // XCD swizzle: each XCD (bx&7) works one task at a time -> task weights L2-resident.
  const int t  = ((bx & 7) << 3) | (bx >> 9);
  const int rb = (bx >> 3) & 63;

  const int lane = tid & 63;
  const int w    = tid >> 6;       // wave id 0..3
  const int quad = lane >> 4;
  const int l15  = lane & 15;

  f32x4 zero4 = {0.f, 0.f, 0.f, 0.f};
  f32x4 acc[4][4];
  #pragma unroll
  for (int rt = 0; rt < 4; ++rt)
    #pragma unroll
    for (int ct = 0; ct < 4; ++ct) acc[rt][ct] = zero4;

  half8 a0[4], a1[4], b[4];

  // ================= Phase 1: GEMM1 (K=512), barrier-free, frags direct from L2 =================
  {
    const half8* pa = tfv + ((size_t)rb * 4096 + quad * 16 + l15);
    const half8* pb = w1v + ((size_t)t * 16384 + w * 4096 + quad * 16 + l15);
    LD_A4(a0, pa);                                     // ks0
    b[0] = pb[0]; b[1] = pb[64]; b[2] = pb[128]; b[3] = pb[192];   // ks0
    a1[0] = pa[256]; a1[1] = pa[320]; a1[2] = pa[384]; a1[3] = pa[448]; // ks1
    pa += 512;            // next A load = ks2
    pb += 256;            // next B load = ks1
    #pragma unroll 1
    for (int ks = 0; ks < 14; ks += 2) {
      STEP_RELOAD(a0, acc, pb); pb += 256;   // uses ks, b <- ks+1
      LD_A4(a0, pa);            pa += 256;   // a0 <- ks+2
      STEP_RELOAD(a1, acc, pb); pb += 256;   // uses ks+1, b <- ks+2
      LD_A4(a1, pa);            pa += 256;   // a1 <- ks+3
    }
    STEP_RELOAD(a0, acc, pb);                // ks14, b <- ks15
    STEP_LAST(a1, acc);                      // ks15
  }

  // ================= Phase 2: +b1, LayerNorm, exact GELU -> H' (frag-order f16) in LDS =================
  // All per-task vector loads happen HERE (b1/gamma/beta/b2) to keep phase 1 spill-free.
  float b1v[4], gv[4], bev[4];
  #pragma unroll
  for (int ct = 0; ct < 4; ++ct) {
    b1v[ct] = b1   [t * HDI + w * 64 + ct * 16 + l15];
    gv[ct]  = gamma[t * HDI + w * 64 + ct * 16 + l15];
    bev[ct] = beta [t * HDI + w * 64 + ct * 16 + l15];
  }
  {
    float* b2s = (float*)(smem + LDS_B2);
    int i0 = tid;
    b2s[i0] = (i0 < VDI) ? b2[(size_t)t * VDI + i0] : 0.f;
    int i1 = tid + 256;
    float v = 0.f;
    if (i1 < VDI) v = b2[(size_t)t * VDI + i1];
    else if (i1 == VDI) v = bc[t];
    b2s[i1] = v;
  }
  {
    float* red0 = (float*)(smem + LDS_R0);
    float* red1 = (float*)(smem + LDS_R1);
    #pragma unroll
    for (int rt = 0; rt < 4; ++rt)
      #pragma unroll
      for (int r = 0; r < 4; ++r) {
        float sv = 0.f, qv = 0.f;
        #pragma unroll
        for (int ct = 0; ct < 4; ++ct) {
          float v = acc[rt][ct][r] + b1v[ct];
          acc[rt][ct][r] = v;
          sv += v; qv += v * v;
        }
        sv += __shfl_xor(sv, 1); qv += __shfl_xor(qv, 1);
        sv += __shfl_xor(sv, 2); qv += __shfl_xor(qv, 2);
        sv += __shfl_xor(sv, 4); qv += __shfl_xor(qv, 4);
        sv += __shfl_xor(sv, 8); qv += __shfl_xor(qv, 8);
        if (l15 == 0) {
          int m = rt * 16 + quad * 4 + r;
          red0[w * 64 + m] = sv;
          red1[w * 64 + m] = qv;
        }
      }
    __syncthreads();
    if (tid < 64) {
      float s = red0[tid] + red0[64 + tid] + red0[128 + tid] + red0[192 + tid];
      float q = red1[tid] + red1[64 + tid] + red1[128 + tid] + red1[192 + tid];
      float mu = s * (1.f / HDI);
      float var = q * (1.f / HDI) - mu * mu;
      ((float*)(smem + LDS_MU))[tid] = mu;
      ((float*)(smem + LDS_RS))[tid] = rsqrtf(var + 1e-5f);
    }
    __syncthreads();
    const float* mus = (const float*)(smem + LDS_MU);
    const float* rss = (const float*)(smem + LDS_RS);
    #pragma unroll
    for (int rt = 0; rt < 4; ++rt)
      #pragma unroll
      for (int ct = 0; ct < 4; ++ct) {
        int col = w * 64 + ct * 16 + l15;
        // HP[ks2][rt][quad2][m&15][col&7]: ks2=col>>5, quad2=(col>>3)&3, m&15=quad*4+r
        int base = (((col >> 5) * 4 + rt) * 4 + ((col >> 3) & 3)) * 256
                 + quad * 64 + (l15 & 7) * 2;
        #pragma unroll
        for (int r = 0; r < 4; ++r) {
          int m = rt * 16 + quad * 4 + r;
          float x = (acc[rt][ct][r] - mus[m]) * rss[m];
          x = x * gv[ct] + bev[ct];
          float g = gelu_exact(x);
          *(_Float16*)(smem + LDS_HP + base + r * 16) = (_Float16)g;
        }
      }
    __syncthreads();
  }

  // ================= Phase 3: GEMM2 (2 N-passes of 256, incl. fused wc dot column) =================
  {
    const float* b2s = (const float*)(smem + LDS_B2);
    float* red0 = (float*)(smem + LDS_R0);
    float* red1 = (float*)(smem + LDS_R1);
    const char* ha = smem + LDS_HP + quad * 256 + l15 * 16;

    #pragma unroll 1
    for (int pass = 0; pass < 2; ++pass) {
      const half8* pc = w2v + ((size_t)t * 16384 + pass * 8192 + w * 2048 + quad * 16 + l15);
      f32x4 acc2[4][4];
      #pragma unroll
      for (int rt = 0; rt < 4; ++rt)
        #pragma unroll
        for (int ct = 0; ct < 4; ++ct) acc2[rt][ct] = zero4;

      a0[0] = *(const half8*)(ha);        a0[1] = *(const half8*)(ha + 1024);
      a0[2] = *(const half8*)(ha + 2048); a0[3] = *(const half8*)(ha + 3072);
      b[0] = pc[0]; b[1] = pc[64]; b[2] = pc[128]; b[3] = pc[192];
      a1[0] = *(const half8*)(ha + 4096); a1[1] = *(const half8*)(ha + 5120);
      a1[2] = *(const half8*)(ha + 6144); a1[3] = *(const half8*)(ha + 7168);
      pc += 256;
      #pragma unroll 1
      for (int ks = 0; ks < 6; ks += 2) {
        STEP_RELOAD(a0, acc2, pc); pc += 256;
        {
          const char* h2 = ha + (ks + 2) * 4096;
          a0[0] = *(const half8*)(h2);        a0[1] = *(const half8*)(h2 + 1024);
          a0[2] = *(const half8*)(h2 + 2048); a0[3] = *(const half8*)(h2 + 3072);
        }
        STEP_RELOAD(a1, acc2, pc); pc += 256;
        {
          const char* h3 = ha + (ks + 3) * 4096;
          a1[0] = *(const half8*)(h3);        a1[1] = *(const half8*)(h3 + 1024);
          a1[2] = *(const half8*)(h3 + 2048); a1[3] = *(const half8*)(h3 + 3072);
        }
      }
      STEP_RELOAD(a0, acc2, pc);   // ks6, b <- ks7
      STEP_LAST(a1, acc2);         // ks7

      // epilogue: per-row |v|^2 (cols<484) and dot (col 484 = wc column + b2.c)
      #pragma unroll
      for (int rt = 0; rt < 4; ++rt)
        #pragma unroll
        for (int r = 0; r < 4; ++r) {
          float ssq = 0.f, dtv = 0.f;
          #pragma unroll
          for (int ct = 0; ct < 4; ++ct) {
            int vcol = pass * 256 + w * 64 + ct * 16 + l15;
            float val = acc2[rt][ct][r] + b2s[vcol];
            ssq += (vcol < VDI) ? val * val : 0.f;
            dtv += (vcol == VDI) ? val : 0.f;
          }
          ssq += __shfl_xor(ssq, 1); dtv += __shfl_xor(dtv, 1);
          ssq += __shfl_xor(ssq, 2); dtv += __shfl_xor(dtv, 2);
          ssq += __shfl_xor(ssq, 4); dtv += __shfl_xor(dtv, 4);
          ssq += __shfl_xor(ssq, 8); dtv += __shfl_xor(dtv, 8);
          if (l15 == 0) {
            int m = rt * 16 + quad * 4 + r;
            if (pass == 0) {
              red0[w * 64 + m] = ssq;
            } else {
              red0[w * 64 + m] += ssq;
              red1[w * 64 + m] = dtv;
            }
          }
        }
    }

    __syncthreads();
    if (tid < 64) {
      float ss  = red0[tid] + red0[64 + tid] + red0[128 + tid] + red0[192 + tid];
      float dot = red1[tid] + red1[64 + tid] + red1[128 + tid] + red1[192 + tid];
      float cn = fmaxf(cnorm[t], 1e-8f);
      float vn = fmaxf(sqrtf(ss), 1e-8f);
      float part = 1.0f - dot / (vn * cn);
      part += __shfl_down(part, 32);
      part += __shfl_down(part, 16);
      part += __shfl_down(part, 8);
      part += __shfl_down(part, 4);
      part += __shfl_down(part, 2);
      part += __shfl_down(part, 1);
      if (tid == 0) atomicAdd(accum + t, part);
    }
  }
}

// ================= finalize: mean, argmin =================
extern "C" __global__ void finalize_k(const float* __restrict__ accum, float* __restrict__ out) {
  int t = threadIdx.x;                               // <<<1, 64>>>
  float d = accum[t] * (1.0f / (float)NB);
  out[t] = d;
  float bd = d; int bi = t;
  #pragma unroll
  for (int off = 32; off; off >>= 1) {
    float od = __shfl_xor(bd, off);
    int   oi = __shfl_xor(bi, off);
    if (od < bd || (od == bd && oi < bi)) { bd = od; bi = oi; }   // first-min tie-break
  }
  if (t == 0) out[64] = (float)bi;
}

extern "C" void kernel_launch(void* const* d_in, const int* in_sizes, int n_in,
                              void* d_out, int out_size, void* d_ws, size_t ws_size,
                              hipStream_t stream) {
  const float* t_feat = (const float*)d_in[0];
  const float* W1     = (const float*)d_in[1];
  const float* b1     = (const float*)d_in[2];
  const float* gamma  = (const float*)d_in[3];
  const float* beta   = (const float*)d_in[4];
  const float* W2     = (const float*)d_in[5];
  const float* b2     = (const float*)d_in[6];
  const float* cent   = (const float*)d_in[7];

  char* ws = (char*)d_ws;   // requires ws_size >= ~38 MiB
  _Float16* tf = (_Float16*)(ws + WS_TF);
  _Float16* w1 = (_Float16*)(ws + WS_W1);
  _Float16* w2 = (_Float16*)(ws + WS_W2);
  float* cnorm = (float*)(ws + WS_CN);
  float* bc    = (float*)(ws + WS_BC);
  float* accum = (float*)(ws + WS_ACC);
  float* out = (float*)d_out;

  prep_all<<<9280, 256, 0, stream>>>(t_feat, W1, W2, b2, cent,
                                     tf, w1, w2, cnorm, bc, accum);
  router_main<<<4096, 256, 0, stream>>>((const half8*)tf, (const half8*)w1, (const half8*)w2,
                                        b1, gamma, beta, b2, bc, cnorm, accum);
  finalize_k<<<1, 64, 0, stream>>>(accum, out);
}

// Round 3
// 317.934 us; speedup vs baseline: 1.5591x; 1.0837x over previous
//
#include <hip/hip_runtime.h>
#include <math.h>

// ---------------- problem constants ----------------
#define TASKS 64
#define NB    4096
#define TDI   512     // token dim (K of GEMM1)
#define HDI   256     // hidden dim
#define VDI   484     // visual dim (padded to 512; row 484 = wc = W2^T.c fused dot column)

// ---------------- ws layout (bytes): frag-order (pre-swizzled) fp16 arrays ----------------
// tf : [64 rb][16 ks][4 rt][4 q][16 l15][8h]  f16  (4 MB)   unit strides: l15=1,q=16,rt=64,ks=256,rb=4096
// w1 : [64 t][4 w][16 ks][4 ct][4 q][16 l15][8h]   (16 MB)  strides: q=16,ct=64,ks=256,w=4096,t=16384
// w2 : [64 t][2 p][4 w][8 ks][4 ct][4 q][16 l15][8h] (16MB)  strides: q=16,ct=64,ks=256,w=2048,p=8192,t=16384
#define WS_TF   ((size_t)0)
#define WS_W1   ((size_t)4194304)
#define WS_W2   ((size_t)20971520)
#define WS_CN   ((size_t)37748736)                // 64 f32 centroid norms
#define WS_BC   ((size_t)37748992)                // 64 f32 b2.c
#define WS_ACC  ((size_t)37749248)                // 64 f32 distance accumulators

// ---------------- LDS layout (bytes): 37376 total ----------------
// HP: [8 ks][4 rt][4 q][16 l15][8h] f16 = 32768  (frag-order for GEMM2 A)
#define LDS_HP 0
#define LDS_B2 32768      // 512 f32: b2 (col 484 = b2.c, 485.. = 0)
#define LDS_R0 34816      // 256 f32: [4w][64m]
#define LDS_R1 35840      // 256 f32
#define LDS_MU 36864      // 64 f32
#define LDS_RS 37120      // 64 f32
#define SMEM_BYTES 37376

typedef _Float16 half8 __attribute__((ext_vector_type(8)));
typedef float    f32x4 __attribute__((ext_vector_type(4)));

#define MFMA16(a, b, c) __builtin_amdgcn_mfma_f32_16x16x32_f16((a), (b), (c), 0, 0, 0)

// Exact-GELU via Abramowitz-Stegun 7.1.26 erf (|err| <= 1.5e-7), ~14 VALU ops, branch-free.
__device__ __forceinline__ float gelu_exact(float x) {
  float az = fabsf(x) * 0.70710678118654752f;          // |x|/sqrt(2)
  float d  = fmaf(0.3275911f, az, 1.0f);
  float t; asm("v_rcp_f32 %0, %1" : "=v"(t) : "v"(d));
  float p  = fmaf(t, 1.061405429f, -1.453152027f);
  p = fmaf(t, p, 1.421413741f);
  p = fmaf(t, p, -0.284496736f);
  p = fmaf(t, p, 0.254829592f);
  p = p * t;
  float m = az * az * -1.4426950408889634f;            // -z^2 * log2(e)
  float e; asm("v_exp_f32 %0, %1" : "=v"(e) : "v"(m)); // 2^m = exp(-z^2)
  float er = fmaf(-p, e, 1.0f);                        // erf(|z|)
  er = copysignf(er, x);
  float hx = 0.5f * x;
  return fmaf(hx, er, hx);                             // 0.5*x*(1+erf)
}

// ================= prepass: fp32 -> frag-order fp16 via LDS tile transpose =================
// Each tile block: read [64 rows x 128 k] f32 fully coalesced -> LDS f16 (row +16B pad)
// -> emit 1024 output-linear 16B units fully coalesced (frag chunks are contiguous).
// Blocks: [0,256) tf (rb,kq) | [256,1280) W1 (t,w,kq) | [1280,2304) W2 (t,p,w,kq) |
//         [2304,2368) per-task (wc row, cnorm, b2.c, accum).
extern "C" __global__ void prep_all(const float* __restrict__ t_feat,
                                    const float* __restrict__ W1,
                                    const float* __restrict__ W2,
                                    const float* __restrict__ b2,
                                    const float* __restrict__ cent,
                                    _Float16* __restrict__ tf,
                                    _Float16* __restrict__ w1,
                                    _Float16* __restrict__ w2,
                                    float* __restrict__ cnorm,
                                    float* __restrict__ bc,
                                    float* __restrict__ accum) {
  __shared__ __align__(16) char pbuf[17408];           // 64 rows x 272B (128 f16 + 16B pad)
  const int bid = blockIdx.x, tid = threadIdx.x;

  if (bid < 2304) {
    const float* src;        // f32 base (pre-offset by kq*128 within row)
    half8* dst;              // output chunk base (1024 contiguous 16B units)
    int w2vdBase = -1;       // >=0: W2 tile, rows vd = w2vdBase + row_local

    if (bid < 256) {                         // tf: rb = bid>>2, kq = bid&3
      int rb = bid >> 2, kq = bid & 3;
      src = t_feat + (size_t)rb * 64 * 512 + kq * 128;
      dst = (half8*)tf + ((size_t)rb * 4096 + kq * 1024);
    } else if (bid < 1280) {                 // W1
      int g = bid - 256;
      int t = g >> 4, w_ = (g >> 2) & 3, kq = g & 3;
      src = W1 + ((size_t)t * 256 + w_ * 64) * 512 + kq * 128;
      dst = (half8*)w1 + ((size_t)t * 16384 + w_ * 4096 + kq * 1024);
    } else {                                 // W2
      int g = bid - 1280;
      int t = g >> 4, sub = g & 15;
      int p = sub >> 3, w_ = (sub >> 1) & 3, kq = sub & 1;
      src = W2 + (size_t)t * 484 * 256 + kq * 128;
      w2vdBase = p * 256 + w_ * 64;
      dst = (half8*)w2 + ((size_t)t * 16384 + p * 8192 + w_ * 2048 + kq * 1024);
    }

    // ---- stage 1: coalesced f32 read -> f16 LDS tile ----
    const int srcStride = (w2vdBase < 0) ? 512 : 256;  // tf/W1 rows are 512 f32, W2 rows 256
    ushort* lds = (ushort*)pbuf;
    #pragma unroll
    for (int j = 0; j < 8; ++j) {
      int f = j * 256 + tid;                 // float4 index in [0, 2048)
      int row = f >> 5, kc = f & 31;         // 32 float4 per row
      float4 v = make_float4(0.f, 0.f, 0.f, 0.f);
      if (w2vdBase < 0) {
        v = ((const float4*)(src + (size_t)row * srcStride))[kc];
      } else {
        int vd = w2vdBase + row;
        if (vd < VDI) v = ((const float4*)(src + (size_t)vd * 256))[kc];
      }
      _Float16 h4[4] = {(_Float16)v.x, (_Float16)v.y, (_Float16)v.z, (_Float16)v.w};
      *(ushort4*)(&lds[row * 136 + kc * 4]) = *(const ushort4*)h4;
    }
    __syncthreads();

    // ---- stage 2: LDS -> output-linear units, fully coalesced 16B stores ----
    #pragma unroll
    for (int j = 0; j < 4; ++j) {
      int u = j * 256 + tid;                 // unit index in [0, 1024)
      int ksl = u >> 8, rg = (u >> 6) & 3, q = (u >> 4) & 3, l15 = u & 15;
      int row = rg * 16 + l15, k8l = ksl * 4 + q;
      half8 val = *(const half8*)(pbuf + row * 272 + k8l * 16);
      if (w2vdBase >= 0 && (w2vdBase + row) == VDI) continue;   // wc row: task block owns it
      dst[u] = val;
    }
  } else {                                   // per-task: wc row, cnorm, b2.c, accum init
    int t = bid - 2304;
    int h = tid;                             // 0..255
    float* redc = (float*)pbuf;
    float* redb = (float*)(pbuf + 1024);
    float wcv = 0.f;
    for (int v = 0; v < VDI; ++v)
      wcv += W2[((size_t)t * VDI + v) * HDI + h] * cent[(size_t)t * VDI + v];
    // vd=484 -> p=1, w=3, ct=2, l15=4 ; ks = h>>5, q=(h>>3)&3, within-unit h&7
    {
      int ks = h >> 5, q = (h >> 3) & 3;
      size_t o = (size_t)t * 16384 + 8192 + 3 * 2048 + ks * 256 + 2 * 64 + q * 16 + 4;
      w2[o * 8 + (h & 7)] = (_Float16)wcv;
    }
    float c2 = 0.f, b2c = 0.f;
    for (int v = h; v < VDI; v += 256) {
      float c = cent[(size_t)t * VDI + v];
      c2 += c * c;
      b2c += b2[(size_t)t * VDI + v] * c;
    }
    redc[tid] = c2; redb[tid] = b2c;
    __syncthreads();
    if (tid < 64) {
      c2  = redc[tid] + redc[tid + 64] + redc[tid + 128] + redc[tid + 192];
      b2c = redb[tid] + redb[tid + 64] + redb[tid + 128] + redb[tid + 192];
      #pragma unroll
      for (int off = 32; off; off >>= 1) { c2 += __shfl_xor(c2, off); b2c += __shfl_xor(b2c, off); }
      if (tid == 0) { cnorm[t] = sqrtf(c2); bc[t] = b2c; accum[t] = 0.f; }
    }
  }
}

// ============ fused main: 256 thr / 4 waves / 64x64 per wave, 4 blocks/CU ============
// Spill-free target: phase 1 live ~124 (acc 64 + a0/a1/b 48 + ptrs), phase 3 live ~106
// (acc2 64 + a0/b 32 + ptrs; A single-buffered from LDS with reload-after-last-use),
// phase 2 rt-outer keeps only 8 mus/rss live. All per-task vector loads sit in barrier
// shadows. s_setprio(1) around MFMA clusters (4 de-phased blocks/CU -> role diversity).

#define STEP_RELOAD(A, ACC, PB) do {                                           \
  __builtin_amdgcn_s_setprio(1);                                               \
  _Pragma("unroll") for (int ct_ = 0; ct_ < 4; ++ct_) {                        \
    ACC[0][ct_] = MFMA16(A[0], b[ct_], ACC[0][ct_]);                           \
    ACC[1][ct_] = MFMA16(A[1], b[ct_], ACC[1][ct_]);                           \
    ACC[2][ct_] = MFMA16(A[2], b[ct_], ACC[2][ct_]);                           \
    ACC[3][ct_] = MFMA16(A[3], b[ct_], ACC[3][ct_]);                           \
    b[ct_] = (PB)[ct_ * 64];                                                   \
  }                                                                            \
  __builtin_amdgcn_s_setprio(0);                                               \
} while (0)

#define STEP_LAST(A, ACC) do {                                                 \
  __builtin_amdgcn_s_setprio(1);                                               \
  _Pragma("unroll") for (int ct_ = 0; ct_ < 4; ++ct_) {                        \
    ACC[0][ct_] = MFMA16(A[0], b[ct_], ACC[0][ct_]);                           \
    ACC[1][ct_] = MFMA16(A[1], b[ct_], ACC[1][ct_]);                           \
    ACC[2][ct_] = MFMA16(A[2], b[ct_], ACC[2][ct_]);                           \
    ACC[3][ct_] = MFMA16(A[3], b[ct_], ACC[3][ct_]);                           \
  }                                                                            \
  __builtin_amdgcn_s_setprio(0);                                               \
} while (0)

#define LD_A4(D, P) do { D[0] = (P)[0]; D[1] = (P)[64]; D[2] = (P)[128]; D[3] = (P)[192]; } while (0)

// Phase-3 step: 16 MFMA; B (global) reloaded per-ct (12-MFMA gap); A (LDS) single-buffered,
// reloaded interleaved with the ct=3 MFMAs (3..15-MFMA gap covers LDS latency at 4 waves).
#define P3_STEP(ACC, HN) do {                                                  \
  __builtin_amdgcn_s_setprio(1);                                               \
  ACC[0][0]=MFMA16(a0[0],b[0],ACC[0][0]); ACC[1][0]=MFMA16(a0[1],b[0],ACC[1][0]); \
  ACC[2][0]=MFMA16(a0[2],b[0],ACC[2][0]); ACC[3][0]=MFMA16(a0[3],b[0],ACC[3][0]); \
  b[0]=pc[0];                                                                  \
  ACC[0][1]=MFMA16(a0[0],b[1],ACC[0][1]); ACC[1][1]=MFMA16(a0[1],b[1],ACC[1][1]); \
  ACC[2][1]=MFMA16(a0[2],b[1],ACC[2][1]); ACC[3][1]=MFMA16(a0[3],b[1],ACC[3][1]); \
  b[1]=pc[64];                                                                 \
  ACC[0][2]=MFMA16(a0[0],b[2],ACC[0][2]); ACC[1][2]=MFMA16(a0[1],b[2],ACC[1][2]); \
  ACC[2][2]=MFMA16(a0[2],b[2],ACC[2][2]); ACC[3][2]=MFMA16(a0[3],b[2],ACC[3][2]); \
  b[2]=pc[128];                                                                \
  ACC[0][3]=MFMA16(a0[0],b[3],ACC[0][3]); a0[0]=*(const half8*)(HN);           \
  ACC[1][3]=MFMA16(a0[1],b[3],ACC[1][3]); a0[1]=*(const half8*)((HN)+1024);    \
  ACC[2][3]=MFMA16(a0[2],b[3],ACC[2][3]); a0[2]=*(const half8*)((HN)+2048);    \
  ACC[3][3]=MFMA16(a0[3],b[3],ACC[3][3]); a0[3]=*(const half8*)((HN)+3072);    \
  b[3]=pc[192]; pc+=256;                                                       \
  __builtin_amdgcn_s_setprio(0);                                               \
} while (0)

extern "C" __global__ void __launch_bounds__(256, 4)
router_main(const half8* __restrict__ tfv,
            const half8* __restrict__ w1v,
            const half8* __restrict__ w2v,
            const float* __restrict__ b1,
            const float* __restrict__ gamma,
            const float* __restrict__ beta,
            const float* __restrict__ b2,
            const float* __restrict__ bc,
            const float* __restrict__ cnorm,
            float* __restrict__ accum) {
  __shared__ __align__(16) char smem[SMEM_BYTES];

  const int tid = threadIdx.x;
  const int bx  = blockIdx.x;
  // XCD swizzle: each XCD (bx&7) works one task at a time -> task weights L2-resident.
  const int t  = ((bx & 7) << 3) | (bx >> 9);
  const int rb = (bx >> 3) & 63;

  const int lane = tid & 63;
  const int w    = tid >> 6;       // wave id 0..3
  const int quad = lane >> 4;
  const int l15  = lane & 15;

  f32x4 zero4 = {0.f, 0.f, 0.f, 0.f};
  f32x4 acc[4][4];
  #pragma unroll
  for (int rt = 0; rt < 4; ++rt)
    #pragma unroll
    for (int ct = 0; ct < 4; ++ct) acc[rt][ct] = zero4;

  half8 a0[4], a1[4], b[4];

  // ================= Phase 1: GEMM1 (K=512), barrier-free, frags direct from L2 =================
  {
    const half8* pa = tfv + ((size_t)rb * 4096 + quad * 16 + l15);
    const half8* pb = w1v + ((size_t)t * 16384 + w * 4096 + quad * 16 + l15);
    LD_A4(a0, pa);                                     // ks0
    b[0] = pb[0]; b[1] = pb[64]; b[2] = pb[128]; b[3] = pb[192];   // ks0
    a1[0] = pa[256]; a1[1] = pa[320]; a1[2] = pa[384]; a1[3] = pa[448]; // ks1
    pa += 512;            // next A load = ks2
    pb += 256;            // next B load = ks1
    #pragma unroll 1
    for (int ks = 0; ks < 14; ks += 2) {
      STEP_RELOAD(a0, acc, pb); pb += 256;   // uses ks, b <- ks+1
      LD_A4(a0, pa);            pa += 256;   // a0 <- ks+2
      STEP_RELOAD(a1, acc, pb); pb += 256;   // uses ks+1, b <- ks+2
      LD_A4(a1, pa);            pa += 256;   // a1 <- ks+3
    }
    STEP_RELOAD(a0, acc, pb);                // ks14, b <- ks15
    STEP_LAST(a1, acc);                      // ks15
  }

  // ================= Phase 2: +b1, LayerNorm, exact GELU -> H' (frag-order f16) in LDS =================
  float b1v[4];
  #pragma unroll
  for (int ct = 0; ct < 4; ++ct)
    b1v[ct] = b1[t * HDI + w * 64 + ct * 16 + l15];
  {
    float* red0 = (float*)(smem + LDS_R0);
    float* red1 = (float*)(smem + LDS_R1);
    #pragma unroll
    for (int rt = 0; rt < 4; ++rt)
      #pragma unroll
      for (int r = 0; r < 4; ++r) {
        float sv = 0.f, qv = 0.f;
        #pragma unroll
        for (int ct = 0; ct < 4; ++ct) {
          float v = acc[rt][ct][r] + b1v[ct];
          acc[rt][ct][r] = v;
          sv += v; qv += v * v;
        }
        sv += __shfl_xor(sv, 1); qv += __shfl_xor(qv, 1);
        sv += __shfl_xor(sv, 2); qv += __shfl_xor(qv, 2);
        sv += __shfl_xor(sv, 4); qv += __shfl_xor(qv, 4);
        sv += __shfl_xor(sv, 8); qv += __shfl_xor(qv, 8);
        if (l15 == 0) {
          int m = rt * 16 + quad * 4 + r;
          red0[w * 64 + m] = sv;
          red1[w * 64 + m] = qv;
        }
      }
    __syncthreads();
    if (tid < 64) {
      float s = red0[tid] + red0[64 + tid] + red0[128 + tid] + red0[192 + tid];
      float q = red1[tid] + red1[64 + tid] + red1[128 + tid] + red1[192 + tid];
      float mu = s * (1.f / HDI);
      float var = q * (1.f / HDI) - mu * mu;
      ((float*)(smem + LDS_MU))[tid] = mu;
      ((float*)(smem + LDS_RS))[tid] = rsqrtf(var + 1e-5f);
    }
    // barrier-shadow loads: gamma/beta + b2 LDS staging overlap the stats barrier
    float gvv[4], bevv[4];
    #pragma unroll
    for (int ct = 0; ct < 4; ++ct) {
      gvv[ct]  = gamma[t * HDI + w * 64 + ct * 16 + l15];
      bevv[ct] = beta [t * HDI + w * 64 + ct * 16 + l15];
    }
    {
      float* b2s = (float*)(smem + LDS_B2);
      int i0 = tid;
      b2s[i0] = (i0 < VDI) ? b2[(size_t)t * VDI + i0] : 0.f;
      int i1 = tid + 256;
      float v = 0.f;
      if (i1 < VDI) v = b2[(size_t)t * VDI + i1];
      else if (i1 == VDI) v = bc[t];
      b2s[i1] = v;
    }
    __syncthreads();
    const float* mus = (const float*)(smem + LDS_MU);
    const float* rss = (const float*)(smem + LDS_RS);
    #pragma unroll
    for (int rt = 0; rt < 4; ++rt) {
      float m4[4], s4[4];
      #pragma unroll
      for (int r = 0; r < 4; ++r) {
        int m = rt * 16 + quad * 4 + r;
        m4[r] = mus[m]; s4[r] = rss[m];
      }
      #pragma unroll
      for (int ct = 0; ct < 4; ++ct) {
        int col = w * 64 + ct * 16 + l15;
        // HP[ks2][rt][quad2][m&15][col&7]: ks2=col>>5, quad2=(col>>3)&3, m&15=quad*4+r
        int base = (((col >> 5) * 4 + rt) * 4 + ((col >> 3) & 3)) * 256
                 + quad * 64 + (l15 & 7) * 2;
        #pragma unroll
        for (int r = 0; r < 4; ++r) {
          float x = (acc[rt][ct][r] - m4[r]) * s4[r];
          x = x * gvv[ct] + bevv[ct];
          *(_Float16*)(smem + LDS_HP + base + r * 16) = (_Float16)gelu_exact(x);
        }
      }
    }
    __syncthreads();
  }

  // ================= Phase 3: GEMM2 (2 N-passes of 256, incl. fused wc dot column) =================
  {
    const float* b2s = (const float*)(smem + LDS_B2);
    float* red0 = (float*)(smem + LDS_R0);
    float* red1 = (float*)(smem + LDS_R1);
    const char* ha = smem + LDS_HP + quad * 256 + l15 * 16;

    #pragma unroll 1
    for (int pass = 0; pass < 2; ++pass) {
      const half8* pc = w2v + ((size_t)t * 16384 + pass * 8192 + w * 2048 + quad * 16 + l15);
      f32x4 acc2[4][4];
      #pragma unroll
      for (int rt = 0; rt < 4; ++rt)
        #pragma unroll
        for (int ct = 0; ct < 4; ++ct) acc2[rt][ct] = zero4;

      a0[0] = *(const half8*)(ha);        a0[1] = *(const half8*)(ha + 1024);
      a0[2] = *(const half8*)(ha + 2048); a0[3] = *(const half8*)(ha + 3072);
      b[0] = pc[0]; b[1] = pc[64]; b[2] = pc[128]; b[3] = pc[192];
      pc += 256;
      #pragma unroll 1
      for (int ks = 0; ks < 7; ++ks) {
        P3_STEP(acc2, ha + (ks + 1) * 4096);
      }
      STEP_LAST(a0, acc2);                 // ks7

      // epilogue: per-row |v|^2 (cols<484) and dot (col 484 = wc column + b2.c)
      #pragma unroll
      for (int rt = 0; rt < 4; ++rt)
        #pragma unroll
        for (int r = 0; r < 4; ++r) {
          float ssq = 0.f, dtv = 0.f;
          #pragma unroll
          for (int ct = 0; ct < 4; ++ct) {
            int vcol = pass * 256 + w * 64 + ct * 16 + l15;
            float val = acc2[rt][ct][r] + b2s[vcol];
            ssq += (vcol < VDI) ? val * val : 0.f;
            dtv += (vcol == VDI) ? val : 0.f;
          }
          ssq += __shfl_xor(ssq, 1); dtv += __shfl_xor(dtv, 1);
          ssq += __shfl_xor(ssq, 2); dtv += __shfl_xor(dtv, 2);
          ssq += __shfl_xor(ssq, 4); dtv += __shfl_xor(dtv, 4);
          ssq += __shfl_xor(ssq, 8); dtv += __shfl_xor(dtv, 8);
          if (l15 == 0) {
            int m = rt * 16 + quad * 4 + r;
            if (pass == 0) {
              red0[w * 64 + m] = ssq;
            } else {
              red0[w * 64 + m] += ssq;
              red1[w * 64 + m] = dtv;
            }
          }
        }
    }

    __syncthreads();
    if (tid < 64) {
      float ss  = red0[tid] + red0[64 + tid] + red0[128 + tid] + red0[192 + tid];
      float dot = red1[tid] + red1[64 + tid] + red1[128 + tid] + red1[192 + tid];
      float cn = fmaxf(cnorm[t], 1e-8f);
      float vn = fmaxf(sqrtf(ss), 1e-8f);
      float part = 1.0f - dot / (vn * cn);
      part += __shfl_down(part, 32);
      part += __shfl_down(part, 16);
      part += __shfl_down(part, 8);
      part += __shfl_down(part, 4);
      part += __shfl_down(part, 2);
      part += __shfl_down(part, 1);
      if (tid == 0) atomicAdd(accum + t, part);
    }
  }
}

// ================= finalize: mean, argmin =================
extern "C" __global__ void finalize_k(const float* __restrict__ accum, float* __restrict__ out) {
  int t = threadIdx.x;                               // <<<1, 64>>>
  float d = accum[t] * (1.0f / (float)NB);
  out[t] = d;
  float bd = d; int bi = t;
  #pragma unroll
  for (int off = 32; off; off >>= 1) {
    float od = __shfl_xor(bd, off);
    int   oi = __shfl_xor(bi, off);
    if (od < bd || (od == bd && oi < bi)) { bd = od; bi = oi; }   // first-min tie-break
  }
  if (t == 0) out[64] = (float)bi;
}

extern "C" void kernel_launch(void* const* d_in, const int* in_sizes, int n_in,
                              void* d_out, int out_size, void* d_ws, size_t ws_size,
                              hipStream_t stream) {
  const float* t_feat = (const float*)d_in[0];
  const float* W1     = (const float*)d_in[1];
  const float* b1     = (const float*)d_in[2];
  const float* gamma  = (const float*)d_in[3];
  const float* beta   = (const float*)d_in[4];
  const float* W2     = (const float*)d_in[5];
  const float* b2     = (const float*)d_in[6];
  const float* cent   = (const float*)d_in[7];

  char* ws = (char*)d_ws;   // requires ws_size >= ~38 MiB
  _Float16* tf = (_Float16*)(ws + WS_TF);
  _Float16* w1 = (_Float16*)(ws + WS_W1);
  _Float16* w2 = (_Float16*)(ws + WS_W2);
  float* cnorm = (float*)(ws + WS_CN);
  float* bc    = (float*)(ws + WS_BC);
  float* accum = (float*)(ws + WS_ACC);
  float* out = (float*)d_out;

  prep_all<<<2368, 256, 0, stream>>>(t_feat, W1, W2, b2, cent,
                                     tf, w1, w2, cnorm, bc, accum);
  router_main<<<4096, 256, 0, stream>>>((const half8*)tf, (const half8*)w1, (const half8*)w2,
                                        b1, gamma, beta, b2, bc, cnorm, accum);
  finalize_k<<<1, 64, 0, stream>>>(accum, out);
}